// Round 14
// baseline (316.040 us; speedup 1.0000x reference)
//
#include <hip/hip_runtime.h>
#include <hip/hip_bf16.h>

#define T_DIM 4096
#define B_DIM 32
#define I_DIM 512
#define O_DIM 512
#define M_DIM (T_DIM * B_DIM)   // 131072
#define PARAM 0.1f
#define ISCALE 1.1111112f       // 1/(1-p)

#define STRIP 32
#define TAPS 8                  // p^8 = 1e-8 << bf16 eps

typedef __attribute__((ext_vector_type(8))) short bf16x8;
typedef __attribute__((ext_vector_type(4))) float f32x4;

__device__ __forceinline__ unsigned short f2bf(float f) {
    union { __hip_bfloat16 b; unsigned short u; } cv;
    cv.b = __float2bfloat16(f);
    return cv.u;
}

// --- W fp32 -> bf16 (0.5 MB, ws offset 0) ---
__global__ __launch_bounds__(256) void wcvt_kernel(const float* __restrict__ W,
                                                   unsigned short* __restrict__ Wb) {
    const int i = (blockIdx.x * 256 + threadIdx.x) * 4;
    f32x4 v = *(const f32x4*)(W + i);
    ushort4 o;
    o.x = f2bf(v[0]); o.y = f2bf(v[1]); o.z = f2bf(v[2]); o.w = f2bf(v[3]);
    *(ushort4*)(Wb + i) = o;
}

// --- EMA over raw X (linearity: EMA(XW+b) = EMA(X)W + s[t]*b). Strip-parallel,
// TAPS warm-up reads raw X; bf16 output compacted into d_ws. ---
__global__ __launch_bounds__(256) void xema_kernel(const float* __restrict__ X,
                                                   unsigned short* __restrict__ Xv) {
    const int s   = blockIdx.x >> 4;                 // strip 0..127
    const int blk = blockIdx.x & 15;
    const int col = (blk * 256 + threadIdx.x) * 4;
    const int t0  = s * STRIP;
    const int b   = col >> 9;
    const int o   = col & 511;

    const float* xin = X + (size_t)t0 * 16384 + col;
    unsigned short* xout = Xv + (size_t)(t0 * 32 + b) * 512 + o;

    f32x4 v = {0.f, 0.f, 0.f, 0.f};
    if (s > 0) {
        const float* w = xin - (size_t)TAPS * 16384;
        #pragma unroll
        for (int j = 0; j < TAPS; ++j)
            v = PARAM * v + *(const f32x4*)(w + (size_t)j * 16384);
    }

    f32x4 bufA[4], bufB[4];
    #pragma unroll
    for (int j = 0; j < 4; ++j) bufA[j] = *(const f32x4*)(xin + (size_t)j * 16384);

    #pragma unroll
    for (int i = 0; i < STRIP; i += 8) {
        #pragma unroll
        for (int j = 0; j < 4; ++j)
            bufB[j] = *(const f32x4*)(xin + (size_t)(i + 4 + j) * 16384);
        #pragma unroll
        for (int j = 0; j < 4; ++j) {
            v = PARAM * v + bufA[j];
            ushort4 pk; pk.x = f2bf(v[0]); pk.y = f2bf(v[1]); pk.z = f2bf(v[2]); pk.w = f2bf(v[3]);
            *(ushort4*)(xout + (size_t)(i + j) * 16384) = pk;
        }
        if (i + 8 < STRIP) {
            #pragma unroll
            for (int j = 0; j < 4; ++j)
                bufA[j] = *(const f32x4*)(xin + (size_t)(i + 8 + j) * 16384);
        }
        #pragma unroll
        for (int j = 0; j < 4; ++j) {
            v = PARAM * v + bufB[j];
            ushort4 pk; pk.x = f2bf(v[0]); pk.y = f2bf(v[1]); pk.z = f2bf(v[2]); pk.w = f2bf(v[3]);
            *(ushort4*)(xout + (size_t)(i + 4 + j) * 16384) = pk;
        }
    }
}

// --- GEMM: barrier-free, B-panel-resident, locality-fixed. Block = 256 thr /
// 4 waves, owns 256 rows x 64 W-cols. B panel (64 cols x K=512, 64KB LDS)
// staged once -> one barrier total. Main loop free-runs: a-frags = contiguous
// 16B global loads (read-once per block), b-frags from read-only swizzled LDS,
// swapped-operand MFMA -> float4 epilogue. Mapping: the 8 col-group blocks of
// one 256-row chunk are consecutive within an XCD (1x HBM + 7x L2); concurrent
// per-XCD A working set ~4MB = L2 size (fixes R12's 612MB thrash). ---
__global__ __launch_bounds__(256, 4) void gemm_kernel(const unsigned short* __restrict__ Xv,
                                                      const unsigned short* __restrict__ Wb,
                                                      const float* __restrict__ bias,
                                                      float* __restrict__ Y) {
    __shared__ __align__(16) short Bs[64 * 512];   // 64 KB

    const int tid  = threadIdx.x;
    const int lane = tid & 63;
    const int wave = tid >> 6;                 // 0..3 = 64-row group

    const int xcd  = blockIdx.x & 7;
    const int idx  = blockIdx.x >> 3;          // 0..511
    const int colg = idx & 7;                  // inner: 8 col-groups share rows
    const int rowc = idx >> 3;                 // 0..63 row-chunks per XCD
    const int row0 = (xcd * 64 + rowc) * 256 + wave * 64;
    const int col0 = colg * 64;

    // Stage B panel once: 16 rounds x 4 rows; wave-uniform row per round,
    // lane = 16B chunk. Pre-swizzled source (involution c^(row&7)).
    {
        const int c = lane;
        #pragma unroll
        for (int s_ = 0; s_ < 16; ++s_) {
            const int row = s_ * 4 + wave;
            const unsigned short* gsrc =
                Wb + (size_t)(col0 + row) * 512 + (c ^ (row & 7)) * 8;
            __builtin_amdgcn_global_load_lds(
                (const __attribute__((address_space(1))) unsigned int*)gsrc,
                (__attribute__((address_space(3))) unsigned int*)(Bs + (size_t)row * 512 + c * 8),
                16, 0, 0);
        }
    }
    __syncthreads();   // the ONLY barrier

    const unsigned short* aBase =
        Xv + (size_t)(row0 + (lane & 15)) * 512 + ((lane >> 4) << 3);

    f32x4 acc[4][4] = {};   // [mf][nf], swapped-operand: reg j = 4 consecutive Y-cols

    #pragma unroll
    for (int ks = 0; ks < 8; ++ks) {
        #pragma unroll
        for (int kk = 0; kk < 2; ++kk) {
            bf16x8 a_[4], b_[4];
            #pragma unroll
            for (int mf = 0; mf < 4; ++mf)
                a_[mf] = *(const bf16x8*)(aBase + (size_t)mf * 16 * 512 + ks * 64 + kk * 32);
            #pragma unroll
            for (int nf = 0; nf < 4; ++nf) {
                const int r  = nf * 16 + (lane & 15);
                const int cc = ks * 8 + kk * 4 + (lane >> 4);
                b_[nf] = *(const bf16x8*)((const char*)Bs + r * 1024 + ((cc ^ (r & 7)) << 4));
            }
            #pragma unroll
            for (int mf = 0; mf < 4; ++mf)
                #pragma unroll
                for (int nf = 0; nf < 4; ++nf)
                    acc[mf][nf] = __builtin_amdgcn_mfma_f32_16x16x32_bf16(
                        b_[nf], a_[mf], acc[mf][nf], 0, 0, 0);   // swapped -> Y^T frag
        }
    }

    // Epilogue: Y = acc + s[t]*bias, float4 stores. t offset within 64 rows = mf>>1.
    float sc2[2];
    #pragma unroll
    for (int tt = 0; tt < 2; ++tt) {
        const int t_ = (row0 >> 5) + tt;
        sc2[tt] = (1.0f - __expf(-2.3025851f * (float)(t_ + 1))) * ISCALE;
    }
    f32x4 bvv[4];
    #pragma unroll
    for (int nf = 0; nf < 4; ++nf)
        bvv[nf] = *(const f32x4*)(bias + col0 + nf * 16 + ((lane >> 4) << 2));

    #pragma unroll
    for (int mf = 0; mf < 4; ++mf) {
        const int grow = row0 + mf * 16 + (lane & 15);
        const float sc = sc2[mf >> 1];
        #pragma unroll
        for (int nf = 0; nf < 4; ++nf) {
            const int gcol = col0 + nf * 16 + ((lane >> 4) << 2);
            f32x4 out;
            #pragma unroll
            for (int e = 0; e < 4; ++e) out[e] = acc[mf][nf][e] + sc * bvv[nf][e];
            *(f32x4*)(Y + (size_t)grow * O_DIM + gcol) = out;
        }
    }
}

extern "C" void kernel_launch(void* const* d_in, const int* in_sizes, int n_in,
                              void* d_out, int out_size, void* d_ws, size_t ws_size,
                              hipStream_t stream) {
    const float* X    = (const float*)d_in[0];
    const float* W    = (const float*)d_in[1];
    const float* bias = (const float*)d_in[2];
    float* Y = (float*)d_out;
    unsigned short* Wb = (unsigned short*)d_ws;                       // 512 KB
    unsigned short* Xv = (unsigned short*)((char*)d_ws + (1 << 20));  // 134 MB

    wcvt_kernel<<<dim3(O_DIM * I_DIM / (256 * 4)), dim3(256), 0, stream>>>(W, Wb);
    xema_kernel<<<dim3((T_DIM / STRIP) * 16), dim3(256), 0, stream>>>(X, Xv);
    gemm_kernel<<<dim3((M_DIM / 256) * (O_DIM / 64)), dim3(256), 0, stream>>>(Xv, Wb, bias, Y);
}

// Round 15
// 304.834 us; speedup vs baseline: 1.0368x; 1.0368x over previous
//
#include <hip/hip_runtime.h>
#include <hip/hip_bf16.h>

#define T_DIM 4096
#define B_DIM 32
#define I_DIM 512
#define O_DIM 512
#define M_DIM (T_DIM * B_DIM)   // 131072
#define PARAM 0.1f
#define ISCALE 1.1111112f       // 1/(1-p)

#define STRIP 32
#define TAPS 8                  // p^8 = 1e-8 << bf16 eps

typedef __attribute__((ext_vector_type(8))) short bf16x8;
typedef __attribute__((ext_vector_type(4))) float f32x4;

__device__ __forceinline__ unsigned short f2bf(float f) {
    union { __hip_bfloat16 b; unsigned short u; } cv;
    cv.b = __float2bfloat16(f);
    return cv.u;
}

// --- W fp32 -> bf16 (0.5 MB, ws offset 0) ---
__global__ __launch_bounds__(256) void wcvt_kernel(const float* __restrict__ W,
                                                   unsigned short* __restrict__ Wb) {
    const int i = (blockIdx.x * 256 + threadIdx.x) * 4;
    f32x4 v = *(const f32x4*)(W + i);
    ushort4 o;
    o.x = f2bf(v[0]); o.y = f2bf(v[1]); o.z = f2bf(v[2]); o.w = f2bf(v[3]);
    *(ushort4*)(Wb + i) = o;
}

// --- EMA over raw X (linearity: EMA(XW+b) = EMA(X)W + s[t]*b). Strip-parallel,
// TAPS warm-up reads raw X; bf16 output compacted into d_ws. ---
__global__ __launch_bounds__(256) void xema_kernel(const float* __restrict__ X,
                                                   unsigned short* __restrict__ Xv) {
    const int s   = blockIdx.x >> 4;                 // strip 0..127
    const int blk = blockIdx.x & 15;
    const int col = (blk * 256 + threadIdx.x) * 4;
    const int t0  = s * STRIP;
    const int b   = col >> 9;
    const int o   = col & 511;

    const float* xin = X + (size_t)t0 * 16384 + col;
    unsigned short* xout = Xv + (size_t)(t0 * 32 + b) * 512 + o;

    f32x4 v = {0.f, 0.f, 0.f, 0.f};
    if (s > 0) {
        const float* w = xin - (size_t)TAPS * 16384;
        #pragma unroll
        for (int j = 0; j < TAPS; ++j)
            v = PARAM * v + *(const f32x4*)(w + (size_t)j * 16384);
    }

    f32x4 bufA[4], bufB[4];
    #pragma unroll
    for (int j = 0; j < 4; ++j) bufA[j] = *(const f32x4*)(xin + (size_t)j * 16384);

    #pragma unroll
    for (int i = 0; i < STRIP; i += 8) {
        #pragma unroll
        for (int j = 0; j < 4; ++j)
            bufB[j] = *(const f32x4*)(xin + (size_t)(i + 4 + j) * 16384);
        #pragma unroll
        for (int j = 0; j < 4; ++j) {
            v = PARAM * v + bufA[j];
            ushort4 pk; pk.x = f2bf(v[0]); pk.y = f2bf(v[1]); pk.z = f2bf(v[2]); pk.w = f2bf(v[3]);
            *(ushort4*)(xout + (size_t)(i + j) * 16384) = pk;
        }
        if (i + 8 < STRIP) {
            #pragma unroll
            for (int j = 0; j < 4; ++j)
                bufA[j] = *(const f32x4*)(xin + (size_t)(i + 8 + j) * 16384);
        }
        #pragma unroll
        for (int j = 0; j < 4; ++j) {
            v = PARAM * v + bufB[j];
            ushort4 pk; pk.x = f2bf(v[0]); pk.y = f2bf(v[1]); pk.z = f2bf(v[2]); pk.w = f2bf(v[3]);
            *(ushort4*)(xout + (size_t)(i + 4 + j) * 16384) = pk;
        }
    }
}

// --- GEMM: barrier-free main loop, B-panel-resident (R14) with two fixes:
// (1) launch_bounds(256,2) + explicit 3-slot A-fragment pipeline (issue ks+2's
//     loads before computing ks) -> ~1000cy latency cover, ~196 VGPR.
// (2) B-LDS as 8 per-K-step subtiles [64 cols][64 k], 128B rows + involution
//     swizzle — the exact ds_read pattern measured conflict-free in R9/R13.
// Block = 256 thr / 4 waves, owns 256 rows x 64 W-cols; B staged once (one
// barrier); swapped-operand MFMA -> Y^T frags -> float4 epilogue. XCD map:
// 8 col-group blocks of one row-chunk adjacent per XCD (FETCH 80MB, R14). ---
__global__ __launch_bounds__(256, 2) void gemm_kernel(const unsigned short* __restrict__ Xv,
                                                      const unsigned short* __restrict__ Wb,
                                                      const float* __restrict__ bias,
                                                      float* __restrict__ Y) {
    __shared__ __align__(16) short Bs[8 * 64 * 64];   // 64 KB: 8 subtiles of 8KB

    const int tid  = threadIdx.x;
    const int lane = tid & 63;
    const int wave = tid >> 6;                 // 0..3 = 64-row group

    const int xcd  = blockIdx.x & 7;
    const int idx  = blockIdx.x >> 3;          // 0..511
    const int colg = idx & 7;                  // inner: 8 col-groups share rows
    const int rowc = idx >> 3;                 // 0..63 row-chunks per XCD
    const int row0 = (xcd * 64 + rowc) * 256 + wave * 64;
    const int col0 = colg * 64;

    // --- Stage B once into per-K-step subtiles. Subtile ks: [64 rows][64 k],
    // row stride 128B; global chunk cs = c ^ (r&7) lands at LDS slot c. ---
    {
        const int c  = tid & 7;                // 16B chunk within 128B row
        const int rr = tid >> 3;               // 0..31
        #pragma unroll
        for (int ks = 0; ks < 8; ++ks) {
            #pragma unroll
            for (int q = 0; q < 2; ++q) {
                const int r  = q * 32 + rr;
                const int cs = c ^ (r & 7);
                const unsigned short* gsrc =
                    Wb + (size_t)(col0 + r) * 512 + ks * 64 + cs * 8;
                __builtin_amdgcn_global_load_lds(
                    (const __attribute__((address_space(1))) unsigned int*)gsrc,
                    (__attribute__((address_space(3))) unsigned int*)
                        (Bs + (size_t)ks * 4096 + (q * 256 + tid) * 8),
                    16, 0, 0);
            }
        }
    }

    const unsigned short* aBase =
        Xv + (size_t)(row0 + (lane & 15)) * 512 + ((lane >> 4) << 3);

    // 3-slot A-fragment pipeline: ap[slot][mf*2+kk]. All indices compile-time
    // under full unroll (rule #20).
    bf16x8 ap[3][8];

    #define LOAD_A(slot, ks)                                                          \
        do {                                                                          \
            _Pragma("unroll")                                                         \
            for (int mf = 0; mf < 4; ++mf)                                            \
                _Pragma("unroll")                                                     \
                for (int kk = 0; kk < 2; ++kk)                                        \
                    ap[slot][mf * 2 + kk] = *(const bf16x8*)(                         \
                        aBase + (size_t)mf * 16 * 512 + (ks) * 64 + kk * 32);         \
        } while (0)

    LOAD_A(0, 0);
    LOAD_A(1, 1);
    __syncthreads();   // the ONLY barrier: B panel + a0/a1 drained

    f32x4 acc[4][4] = {};   // [mf][nf], swapped-operand: reg j = 4 consecutive Y-cols

    #pragma unroll
    for (int ks = 0; ks < 8; ++ks) {
        if (ks + 2 < 8) {
            const int slot = (ks + 2) % 3;
            LOAD_A(slot, ks + 2);
        }
        #pragma unroll
        for (int kk = 0; kk < 2; ++kk) {
            bf16x8 b_[4];
            #pragma unroll
            for (int nf = 0; nf < 4; ++nf) {
                const int r  = nf * 16 + (lane & 15);
                const int cc = kk * 4 + (lane >> 4);
                b_[nf] = *(const bf16x8*)((const char*)Bs + ks * 8192 + r * 128 +
                                          ((cc ^ (r & 7)) << 4));
            }
            #pragma unroll
            for (int mf = 0; mf < 4; ++mf)
                #pragma unroll
                for (int nf = 0; nf < 4; ++nf)
                    acc[mf][nf] = __builtin_amdgcn_mfma_f32_16x16x32_bf16(
                        b_[nf], ap[ks % 3][mf * 2 + kk], acc[mf][nf], 0, 0, 0);
        }
    }

    // Epilogue: Y = acc + s[t]*bias, float4 stores. t offset within 64 rows = mf>>1.
    float sc2[2];
    #pragma unroll
    for (int tt = 0; tt < 2; ++tt) {
        const int t_ = (row0 >> 5) + tt;
        sc2[tt] = (1.0f - __expf(-2.3025851f * (float)(t_ + 1))) * ISCALE;
    }
    f32x4 bvv[4];
    #pragma unroll
    for (int nf = 0; nf < 4; ++nf)
        bvv[nf] = *(const f32x4*)(bias + col0 + nf * 16 + ((lane >> 4) << 2));

    #pragma unroll
    for (int mf = 0; mf < 4; ++mf) {
        const int grow = row0 + mf * 16 + (lane & 15);
        const float sc = sc2[mf >> 1];
        #pragma unroll
        for (int nf = 0; nf < 4; ++nf) {
            const int gcol = col0 + nf * 16 + ((lane >> 4) << 2);
            f32x4 out;
            #pragma unroll
            for (int e = 0; e < 4; ++e) out[e] = acc[mf][nf][e] + sc * bvv[nf][e];
            *(f32x4*)(Y + (size_t)grow * O_DIM + gcol) = out;
        }
    }
    #undef LOAD_A
}

extern "C" void kernel_launch(void* const* d_in, const int* in_sizes, int n_in,
                              void* d_out, int out_size, void* d_ws, size_t ws_size,
                              hipStream_t stream) {
    const float* X    = (const float*)d_in[0];
    const float* W    = (const float*)d_in[1];
    const float* bias = (const float*)d_in[2];
    float* Y = (float*)d_out;
    unsigned short* Wb = (unsigned short*)d_ws;                       // 512 KB
    unsigned short* Xv = (unsigned short*)((char*)d_ws + (1 << 20));  // 134 MB

    wcvt_kernel<<<dim3(O_DIM * I_DIM / (256 * 4)), dim3(256), 0, stream>>>(W, Wb);
    xema_kernel<<<dim3((T_DIM / STRIP) * 16), dim3(256), 0, stream>>>(X, Xv);
    gemm_kernel<<<dim3((M_DIM / 256) * (O_DIM / 64)), dim3(256), 0, stream>>>(Xv, Wb, bias, Y);
}